// Round 6
// baseline (1570.486 us; speedup 1.0000x reference)
//
#include <hip/hip_runtime.h>
#include <hip/hip_bf16.h>
#include <math.h>

// Problem constants
#define B_  64
#define T_  128
#define E_  300
#define H_  256      // hidden per direction
#define G4  1024     // 4*H
#define N2  2048     // both directions' gates
#define GG  512      // G = 2H
#define FH_ 256
#define NC_ 2

typedef __attribute__((ext_vector_type(8))) short short8;
typedef __attribute__((ext_vector_type(4))) float f32x4;
typedef unsigned short ushort_t;
typedef unsigned long long u64;

static __device__ __forceinline__ ushort_t bf16bits(float x) {
    __hip_bfloat16 b = __float2bfloat16(x);
    return __builtin_bit_cast(ushort_t, b);
}
static __device__ __forceinline__ float bf16lo(unsigned v) {
    return __builtin_bit_cast(float, v << 16);
}
static __device__ __forceinline__ float bf16hi(unsigned v) {
    return __builtin_bit_cast(float, v & 0xffff0000u);
}
static __device__ __forceinline__ float sigm(float x) {
    return 1.f / (1.f + __expf(-x));
}
static __device__ __forceinline__ float tanh_fast(float x) {
    const float e = __expf(2.f * x);          // inf-safe: x>>0 -> 1, x<<0 -> -1
    return 1.f - 2.f / (e + 1.f);
}

// ---------------------------------------------------------------------------
// Workspace layout (bytes):
//   0        : hbuf  u64[2 parity][8 group][2 half][16 batch][64 word] = 262144
//   262144   : bias2 (2048 f32)                                        = 8192
//   524288   : wihshuf (128 ntile x 10 ks x 64 lane x 8) bf16          = 1310720
//   8388608  : xprojb (8192 x 2048) bf16                               = 33554432
//   41943040 : S     (64 x 512) f32                                    = 131072
// h-word: [tag:32 | h_odd:bf16 | h_even:bf16]; tag = h-state index (0..128).
// Harness poison 0xAAAAAAAA never equals a tag.
// ---------------------------------------------------------------------------
#define OFF_BIAS  262144
#define OFF_WIH   524288
#define OFF_XPROJ 8388608
#define OFF_S     41943040

// ---------------------------------------------------------------------------
// K_prep: (a) zero parity-0 hbuf (tags=0 == initial h state), (b) bias2,
// (c) w_ih shuffle to B-frag stream order.  Grid 320 x 256.
// ---------------------------------------------------------------------------
__global__ __launch_bounds__(256) void k_prep(
    const float* __restrict__ w_ih_f,
    const float* __restrict__ w_ih_b,
    const float* __restrict__ b_ih_f, const float* __restrict__ b_hh_f,
    const float* __restrict__ b_ih_b, const float* __restrict__ b_hh_b,
    u64*         __restrict__ hbuf,
    float*       __restrict__ bias2,
    ushort_t*    __restrict__ wihshuf) {
    const int idx = blockIdx.x * 256 + threadIdx.x;   // 0..81919

    if (idx < 16384) hbuf[idx] = 0ull;                // parity-0 slab

    if (idx < N2) {
        bias2[idx] = (idx < G4) ? (b_ih_f[idx] + b_hh_f[idx])
                                : (b_ih_b[idx - G4] + b_hh_b[idx - G4]);
    }

    {   // w_ih shuffle, p = idx in [0,81920)
        const int ntile = idx / 640;
        const int r     = idx % 640;
        const int ks    = r / 64;
        const int lane  = r % 64;
        const int n  = ntile * 16 + (lane & 15);
        const int k0 = ks * 32 + ((lane >> 4) << 3);
        const float* src = (n < G4) ? (w_ih_f + (size_t)n * E_)
                                    : (w_ih_b + (size_t)(n - G4) * E_);
        ushort_t o[8];
        #pragma unroll
        for (int j = 0; j < 8; ++j) {
            const int k = k0 + j;
            o[j] = (k < E_) ? bf16bits(src[k]) : (ushort_t)0;
        }
        uint4 pk;
        pk.x = (unsigned)o[0] | ((unsigned)o[1] << 16);
        pk.y = (unsigned)o[2] | ((unsigned)o[3] << 16);
        pk.z = (unsigned)o[4] | ((unsigned)o[5] << 16);
        pk.w = (unsigned)o[6] | ((unsigned)o[7] << 16);
        *(uint4*)(wihshuf + (size_t)idx * 8) = pk;
    }
}

// ---------------------------------------------------------------------------
// K1: xproj GEMM, bf16 MFMA, gather fused (reads glove directly, no xemb).
// grid (128,16) x 256.  LDS-transpose epilogue for coalesced stores.
// ---------------------------------------------------------------------------
__global__ __launch_bounds__(256) void k_xproj_mfma(
    const int*      __restrict__ sentence,
    const float*    __restrict__ glove,
    const ushort_t* __restrict__ wihshuf,
    const float*    __restrict__ bias2,
    ushort_t*       __restrict__ xprojb) {
    __shared__ ushort_t ct[4][16][136];
    const int tid = threadIdx.x;
    const int wave = tid >> 6, lane = tid & 63;
    const int quad = lane >> 4, l15 = lane & 15;
    const int m0 = blockIdx.x * 64 + wave * 16;
    const float* arow = glove + (size_t)sentence[m0 + l15] * E_;
    const ushort_t* wp = wihshuf + (size_t)blockIdx.y * 40960 + lane * 8;

    f32x4 acc[8] = {};
    #pragma unroll
    for (int ks = 0; ks < 10; ++ks) {
        short8 af;
        if (ks < 9) {
            const float* p = arow + ks * 32 + quad * 8;
            float4 lo = *(const float4*)p;
            float4 hi = *(const float4*)(p + 4);
            af[0] = (short)bf16bits(lo.x); af[1] = (short)bf16bits(lo.y);
            af[2] = (short)bf16bits(lo.z); af[3] = (short)bf16bits(lo.w);
            af[4] = (short)bf16bits(hi.x); af[5] = (short)bf16bits(hi.y);
            af[6] = (short)bf16bits(hi.z); af[7] = (short)bf16bits(hi.w);
        } else {
            #pragma unroll
            for (int j = 0; j < 8; ++j) {
                const int k = 288 + quad * 8 + j;
                af[j] = (k < E_) ? (short)bf16bits(arow[k]) : (short)0;
            }
        }
        #pragma unroll
        for (int j = 0; j < 8; ++j) {
            short8 bf = *(const short8*)(wp + (size_t)(j * 10 + ks) * 512);
            acc[j] = __builtin_amdgcn_mfma_f32_16x16x32_bf16(af, bf, acc[j], 0, 0, 0);
        }
    }
    #pragma unroll
    for (int j = 0; j < 8; ++j) {
        const float bias = bias2[blockIdx.y * 128 + j * 16 + l15];
        #pragma unroll
        for (int r = 0; r < 4; ++r)
            ct[wave][quad * 4 + r][j * 16 + l15] = bf16bits(acc[j][r] + bias);
    }
    #pragma unroll
    for (int i = 0; i < 4; ++i) {
        const int row = i * 4 + (lane >> 4);
        uint4 v = *(const uint4*)&ct[wave][row][l15 * 8];
        *(uint4*)(xprojb + (size_t)(m0 + row) * N2 + blockIdx.y * 128 + l15 * 8) = v;
    }
}

// ---------------------------------------------------------------------------
// K2: BiLSTM, PAIRED blocks (fan-in 2), W register-resident, own/partner
// K-split MFMA to hide the LLC handoff.
// 16 blocks x 256 threads. g = blockIdx&7 = (dir d=g&1, batches b0=(g>>1)*16);
// half = blockIdx>>3 owns cells [half*128, half*128+128) (all 4 gates).
// Pair (g, g+8): same XCD under round-robin (speed heuristic only —
// correctness uses agent-scope LLC atomics regardless of placement).
// Wave w = gate w; per wave 8 n-tiles x 8 ks = 64 B-frags in 256 VGPRs.
// ---------------------------------------------------------------------------
__global__ __launch_bounds__(256, 1) void k_lstm_pair(
    const ushort_t* __restrict__ xprojb,   // (64,128,2048) bf16
    const float*    __restrict__ w_hh_f,   // (1024,256) f32
    const float*    __restrict__ w_hh_b,
    const int*      __restrict__ text_len,
    u64*            __restrict__ hbuf,     // [2][8][2][16][64] tagged words
    float*          __restrict__ S)        // (64,512)
{
    __shared__ ushort_t hl[16][264];       // h bf16 [batch][k], pad +8
    __shared__ float    gLDS[4][16][136];  // [gate][batch][cell_local], pad

    const int tid  = threadIdx.x;
    const int g    = blockIdx.x & 7;
    const int half = blockIdx.x >> 3;
    const int ph   = 1 - half;
    const int d    = g & 1;
    const int b0   = (g >> 1) * 16;
    const int c0   = half * 128;
    const int wave = tid >> 6, lane = tid & 63;
    const int quad = lane >> 4, l15 = lane & 15;

    const float* whh = d ? w_hh_b : w_hh_f;

    // ---- preload W B-frags into registers (once): 8 n-tiles x 8 ks ----
    short8 wfrag[8][8];
    #pragma unroll
    for (int nt = 0; nt < 8; ++nt) {
        const int n = wave * 256 + c0 + nt * 16 + l15;
        const float* rowp = whh + (size_t)n * 256;
        #pragma unroll
        for (int ks = 0; ks < 8; ++ks) {
            const float* p = rowp + ks * 32 + quad * 8;
            float4 lo = *(const float4*)p;
            float4 hi = *(const float4*)(p + 4);
            short8 f;
            f[0] = (short)bf16bits(lo.x); f[1] = (short)bf16bits(lo.y);
            f[2] = (short)bf16bits(lo.z); f[3] = (short)bf16bits(lo.w);
            f[4] = (short)bf16bits(hi.x); f[5] = (short)bf16bits(hi.y);
            f[6] = (short)bf16bits(hi.z); f[7] = (short)bf16bits(hi.w);
            wfrag[nt][ks] = f;
        }
    }

    // zero hl (h_0 = 0), then barrier
    for (int i = tid; i < 16 * 264; i += 256) ((ushort_t*)hl)[i] = 0;
    __syncthreads();

    // cell assignment: batch mb, local cells [cl0, cl0+8)
    const int mb  = tid >> 4;
    const int cl0 = (tid & 15) * 8;
    const int lenm = text_len[b0 + mb];
    float cst[8] = {}, ssum[8] = {};

    for (int t = 0; t < T_; ++t) {
        const int tt = d ? (T_ - 1 - t) : t;
        // xproj prefetch (independent of h): 4 x dwordx4, one per gate
        const ushort_t* xp = xprojb +
            ((size_t)(b0 + mb) * T_ + tt) * N2 + d * G4 + c0 + cl0;
        uint4 xv[4];
        #pragma unroll
        for (int q = 0; q < 4; ++q) xv[q] = *(const uint4*)(xp + q * 256);

        // ---- own-half MFMA (no network dependency) ----
        short8 afo[4];
        #pragma unroll
        for (int i = 0; i < 4; ++i)
            afo[i] = *(const short8*)&hl[l15][(half * 4 + i) * 32 + quad * 8];
        f32x4 acc[8] = {};
        #pragma unroll
        for (int i = 0; i < 4; ++i)
            #pragma unroll
            for (int nt = 0; nt < 8; ++nt)
                acc[nt] = __builtin_amdgcn_mfma_f32_16x16x32_bf16(
                    afo[i], wfrag[nt][half * 4 + i], acc[nt], 0, 0, 0);

        // ---- poll partner's tagged words (4 per thread), stage to LDS ----
        {
            const u64* src = hbuf + (size_t)(t & 1) * 16384 + g * 2048 + ph * 1024;
            u64 v[4];
            for (;;) {
                bool ok = true;
                #pragma unroll
                for (int i = 0; i < 4; ++i)
                    v[i] = __hip_atomic_load(src + tid + 256 * i,
                                             __ATOMIC_RELAXED,
                                             __HIP_MEMORY_SCOPE_AGENT);
                #pragma unroll
                for (int i = 0; i < 4; ++i)
                    ok = ok && ((unsigned)(v[i] >> 32) == (unsigned)t);
                if (ok) break;
            }
            #pragma unroll
            for (int i = 0; i < 4; ++i) {
                const int w = tid + 256 * i;
                *(unsigned*)&hl[w >> 6][ph * 128 + (w & 63) * 2] = (unsigned)v[i];
            }
        }
        __syncthreads();   // B1: partner h staged

        // ---- partner-half MFMA ----
        #pragma unroll
        for (int i = 0; i < 4; ++i) {
            short8 afp = *(const short8*)&hl[l15][(ph * 4 + i) * 32 + quad * 8];
            #pragma unroll
            for (int nt = 0; nt < 8; ++nt)
                acc[nt] = __builtin_amdgcn_mfma_f32_16x16x32_bf16(
                    afp, wfrag[nt][ph * 4 + i], acc[nt], 0, 0, 0);
        }
        // gates -> gLDS. C layout: row(batch)=quad*4+r, col(cell)=nt*16+l15
        #pragma unroll
        for (int nt = 0; nt < 8; ++nt)
            #pragma unroll
            for (int r = 0; r < 4; ++r)
                gLDS[wave][quad * 4 + r][nt * 16 + l15] = acc[nt][r];
        __syncthreads();   // B2: gates ready

        // ---- cell update: (mb, cl0..cl0+7) ----
        float gv[4][8];
        #pragma unroll
        for (int q = 0; q < 4; ++q) {
            *(f32x4*)&gv[q][0] = *(const f32x4*)&gLDS[q][mb][cl0];
            *(f32x4*)&gv[q][4] = *(const f32x4*)&gLDS[q][mb][cl0 + 4];
        }
        ushort_t hb[8];
        const bool in_len = (tt < lenm);
        #pragma unroll
        for (int u = 0; u < 8; ++u) {
            const unsigned wi = ((const unsigned*)&xv[0])[u >> 1];
            const unsigned wf = ((const unsigned*)&xv[1])[u >> 1];
            const unsigned wg = ((const unsigned*)&xv[2])[u >> 1];
            const unsigned wo = ((const unsigned*)&xv[3])[u >> 1];
            const float xi = (u & 1) ? bf16hi(wi) : bf16lo(wi);
            const float xf = (u & 1) ? bf16hi(wf) : bf16lo(wf);
            const float xg = (u & 1) ? bf16hi(wg) : bf16lo(wg);
            const float xo = (u & 1) ? bf16hi(wo) : bf16lo(wo);
            const float i_ = sigm(xi + gv[0][u]);
            const float f_ = sigm(xf + gv[1][u]);
            const float g_ = tanh_fast(xg + gv[2][u]);
            const float o_ = sigm(xo + gv[3][u]);
            cst[u] = f_ * cst[u] + i_ * g_;
            const float hn = o_ * tanh_fast(cst[u]);
            if (in_len) ssum[u] += hn;
            hb[u] = bf16bits(hn);
        }
        // own h -> LDS (16B) + tagged words -> LLC (4 x 8B)
        uint4 hp;
        hp.x = (unsigned)hb[0] | ((unsigned)hb[1] << 16);
        hp.y = (unsigned)hb[2] | ((unsigned)hb[3] << 16);
        hp.z = (unsigned)hb[4] | ((unsigned)hb[5] << 16);
        hp.w = (unsigned)hb[6] | ((unsigned)hb[7] << 16);
        *(uint4*)&hl[mb][c0 + cl0] = hp;
        u64* dst = hbuf + (size_t)((t + 1) & 1) * 16384 + g * 2048 +
                   half * 1024 + mb * 64 + (cl0 >> 1);
        const u64 tag = (u64)(unsigned)(t + 1) << 32;
        __hip_atomic_store(dst + 0, tag | (u64)hp.x, __ATOMIC_RELAXED, __HIP_MEMORY_SCOPE_AGENT);
        __hip_atomic_store(dst + 1, tag | (u64)hp.y, __ATOMIC_RELAXED, __HIP_MEMORY_SCOPE_AGENT);
        __hip_atomic_store(dst + 2, tag | (u64)hp.z, __ATOMIC_RELAXED, __HIP_MEMORY_SCOPE_AGENT);
        __hip_atomic_store(dst + 3, tag | (u64)hp.w, __ATOMIC_RELAXED, __HIP_MEMORY_SCOPE_AGENT);
        __syncthreads();   // B3: hl own-half visible; gLDS reusable
    }

    float4 sa, sb;
    sa.x = ssum[0]; sa.y = ssum[1]; sa.z = ssum[2]; sa.w = ssum[3];
    sb.x = ssum[4]; sb.y = ssum[5]; sb.z = ssum[6]; sb.w = ssum[7];
    float* sp = S + (size_t)(b0 + mb) * GG + d * H_ + c0 + cl0;
    *(float4*)sp = sa;
    *(float4*)(sp + 4) = sb;
}

// ---------------------------------------------------------------------------
// K3: head (unchanged).
// ---------------------------------------------------------------------------
__global__ __launch_bounds__(256) void k_head(
    const float* __restrict__ S,
    const int*   __restrict__ text_len,
    const float* __restrict__ gat_w, const float* __restrict__ gat_b,
    const float* __restrict__ fc1_w, const float* __restrict__ fc1_b,
    const float* __restrict__ fc2_w, const float* __restrict__ fc2_b,
    const float* __restrict__ fcf_w, const float* __restrict__ fcf_b,
    float* __restrict__ out)
{
    __shared__ float sb[GG];
    __shared__ float x1[GG];
    __shared__ float x2[FH_];
    __shared__ float x3[FH_];
    const int b = blockIdx.x, tid = threadIdx.x;
    sb[tid]       = S[(size_t)b * GG + tid];
    sb[tid + 256] = S[(size_t)b * GG + tid + 256];
    __syncthreads();
    const float lenf = (float)text_len[b];
    #pragma unroll
    for (int r = 0; r < 2; ++r) {
        const int n = tid + r * 256;
        float acc = gat_b[n] * lenf;
        const float* w = gat_w + (size_t)n * GG;
        for (int k = 0; k < GG; ++k) acc += sb[k] * w[k];
        x1[n] = fmaxf(acc, 0.f);
    }
    __syncthreads();
    {
        float acc = fc1_b[tid];
        const float* w = fc1_w + (size_t)tid * GG;
        for (int k = 0; k < GG; ++k) acc += x1[k] * w[k];
        x2[tid] = fmaxf(acc, 0.f);
    }
    __syncthreads();
    {
        float acc = fc2_b[tid];
        const float* w = fc2_w + (size_t)tid * FH_;
        for (int k = 0; k < FH_; ++k) acc += x2[k] * w[k];
        x3[tid] = fmaxf(acc, 0.f);
    }
    __syncthreads();
    if (tid < NC_) {
        float acc = fcf_b[tid];
        const float* w = fcf_w + (size_t)tid * FH_;
        for (int k = 0; k < FH_; ++k) acc += x3[k] * w[k];
        out[b * NC_ + tid] = acc;
    }
}

// ---------------------------------------------------------------------------
extern "C" void kernel_launch(void* const* d_in, const int* in_sizes, int n_in,
                              void* d_out, int out_size, void* d_ws, size_t ws_size,
                              hipStream_t stream) {
    const int*   sentence = (const int*)  d_in[0];
    const int*   text_len = (const int*)  d_in[4];
    const float* glove    = (const float*)d_in[10];
    const float* w_ih_f   = (const float*)d_in[11];
    const float* w_hh_f   = (const float*)d_in[12];
    const float* b_ih_f   = (const float*)d_in[13];
    const float* b_hh_f   = (const float*)d_in[14];
    const float* w_ih_b   = (const float*)d_in[15];
    const float* w_hh_b   = (const float*)d_in[16];
    const float* b_ih_b   = (const float*)d_in[17];
    const float* b_hh_b   = (const float*)d_in[18];
    const float* gat_w    = (const float*)d_in[19];
    const float* gat_b    = (const float*)d_in[20];
    const float* fc1_w    = (const float*)d_in[21];
    const float* fc1_b    = (const float*)d_in[22];
    const float* fc2_w    = (const float*)d_in[23];
    const float* fc2_b    = (const float*)d_in[24];
    const float* fcf_w    = (const float*)d_in[25];
    const float* fcf_b    = (const float*)d_in[26];
    float* out = (float*)d_out;

    char* ws = (char*)d_ws;
    u64*      hbuf    = (u64*)ws;
    float*    bias2   = (float*)(ws + OFF_BIAS);
    ushort_t* wihshuf = (ushort_t*)(ws + OFF_WIH);
    ushort_t* xprojb  = (ushort_t*)(ws + OFF_XPROJ);
    float*    S       = (float*)(ws + OFF_S);

    k_prep<<<320, 256, 0, stream>>>(w_ih_f, w_ih_b,
                                    b_ih_f, b_hh_f, b_ih_b, b_hh_b,
                                    hbuf, bias2, wihshuf);
    dim3 gx(128, 16);
    k_xproj_mfma<<<gx, 256, 0, stream>>>(sentence, glove, wihshuf, bias2, xprojb);
    k_lstm_pair<<<16, 256, 0, stream>>>(xprojb, w_hh_f, w_hh_b, text_len,
                                        hbuf, S);
    k_head<<<64, 256, 0, stream>>>(S, text_len, gat_w, gat_b,
                                   fc1_w, fc1_b, fc2_w, fc2_b,
                                   fcf_w, fcf_b, out);
}

// Round 7
// 800.805 us; speedup vs baseline: 1.9611x; 1.9611x over previous
//
#include <hip/hip_runtime.h>
#include <hip/hip_bf16.h>
#include <math.h>

// Problem constants
#define B_  64
#define T_  128
#define E_  300
#define H_  256      // hidden per direction
#define G4  1024     // 4*H
#define N2  2048     // both directions' gates
#define GG  512      // G = 2H
#define FH_ 256
#define NC_ 2

typedef __attribute__((ext_vector_type(8))) short short8;
typedef __attribute__((ext_vector_type(4))) float f32x4;
typedef unsigned short ushort_t;
typedef unsigned long long u64;

static __device__ __forceinline__ ushort_t bf16bits(float x) {
    __hip_bfloat16 b = __float2bfloat16(x);
    return __builtin_bit_cast(ushort_t, b);
}
static __device__ __forceinline__ float bf16lo(unsigned v) {
    return __builtin_bit_cast(float, v << 16);
}
static __device__ __forceinline__ float bf16hi(unsigned v) {
    return __builtin_bit_cast(float, v & 0xffff0000u);
}
static __device__ __forceinline__ float sigm(float x) {
    return 1.f / (1.f + __expf(-x));
}
static __device__ __forceinline__ float tanh_fast(float x) {
    const float e = __expf(2.f * x);          // inf-safe
    return 1.f - 2.f / (e + 1.f);
}

// ---------------------------------------------------------------------------
// Workspace layout (bytes):
//   0        : hbuf u64[2 parity][2 dir][4 grp][16 batch][128 word] = 262144
//   262144   : bias2 (2048 f32)                                     = 8192
//   524288   : wihshuf (128 ntile x 10 ks x 64 lane x 8) bf16       = 1310720
//   8388608  : xprojb (8192 x 2048) bf16                            = 33554432
//   41943040 : S     (64 x 512) f32                                 = 131072
// h-word: [tag:32 | h_odd:bf16 | h_even:bf16]; tag = h-state index (0..128).
// Harness poison 0xAAAAAAAA never equals a tag.
// ---------------------------------------------------------------------------
#define OFF_BIAS  262144
#define OFF_WIH   524288
#define OFF_XPROJ 8388608
#define OFF_S     41943040

// ---------------------------------------------------------------------------
// K_prep: (a) zero parity-0 hbuf (tags=0 == initial h for both dirs),
// (b) bias2, (c) w_ih shuffle to B-frag stream order.  Grid 320 x 256.
// ---------------------------------------------------------------------------
__global__ __launch_bounds__(256) void k_prep(
    const float* __restrict__ w_ih_f,
    const float* __restrict__ w_ih_b,
    const float* __restrict__ b_ih_f, const float* __restrict__ b_hh_f,
    const float* __restrict__ b_ih_b, const float* __restrict__ b_hh_b,
    u64*         __restrict__ hbuf,
    float*       __restrict__ bias2,
    ushort_t*    __restrict__ wihshuf) {
    const int idx = blockIdx.x * 256 + threadIdx.x;   // 0..81919

    if (idx < 16384) hbuf[idx] = 0ull;                // parity-0, both dirs

    if (idx < N2) {
        bias2[idx] = (idx < G4) ? (b_ih_f[idx] + b_hh_f[idx])
                                : (b_ih_b[idx - G4] + b_hh_b[idx - G4]);
    }

    {   // w_ih shuffle, p = idx in [0,81920)
        const int ntile = idx / 640;
        const int r     = idx % 640;
        const int ks    = r / 64;
        const int lane  = r % 64;
        const int n  = ntile * 16 + (lane & 15);
        const int k0 = ks * 32 + ((lane >> 4) << 3);
        const float* src = (n < G4) ? (w_ih_f + (size_t)n * E_)
                                    : (w_ih_b + (size_t)(n - G4) * E_);
        ushort_t o[8];
        #pragma unroll
        for (int j = 0; j < 8; ++j) {
            const int k = k0 + j;
            o[j] = (k < E_) ? bf16bits(src[k]) : (ushort_t)0;
        }
        uint4 pk;
        pk.x = (unsigned)o[0] | ((unsigned)o[1] << 16);
        pk.y = (unsigned)o[2] | ((unsigned)o[3] << 16);
        pk.z = (unsigned)o[4] | ((unsigned)o[5] << 16);
        pk.w = (unsigned)o[6] | ((unsigned)o[7] << 16);
        *(uint4*)(wihshuf + (size_t)idx * 8) = pk;
    }
}

// ---------------------------------------------------------------------------
// K1: xproj GEMM, bf16 MFMA, gather fused (reads glove directly).
// grid (128,16) x 256.  LDS-transpose epilogue for coalesced stores.
// (unchanged from R6 — proven correct)
// ---------------------------------------------------------------------------
__global__ __launch_bounds__(256) void k_xproj_mfma(
    const int*      __restrict__ sentence,
    const float*    __restrict__ glove,
    const ushort_t* __restrict__ wihshuf,
    const float*    __restrict__ bias2,
    ushort_t*       __restrict__ xprojb) {
    __shared__ ushort_t ct[4][16][136];
    const int tid = threadIdx.x;
    const int wave = tid >> 6, lane = tid & 63;
    const int quad = lane >> 4, l15 = lane & 15;
    const int m0 = blockIdx.x * 64 + wave * 16;
    const float* arow = glove + (size_t)sentence[m0 + l15] * E_;
    const ushort_t* wp = wihshuf + (size_t)blockIdx.y * 40960 + lane * 8;

    f32x4 acc[8] = {};
    #pragma unroll
    for (int ks = 0; ks < 10; ++ks) {
        short8 af;
        if (ks < 9) {
            const float* p = arow + ks * 32 + quad * 8;
            float4 lo = *(const float4*)p;
            float4 hi = *(const float4*)(p + 4);
            af[0] = (short)bf16bits(lo.x); af[1] = (short)bf16bits(lo.y);
            af[2] = (short)bf16bits(lo.z); af[3] = (short)bf16bits(lo.w);
            af[4] = (short)bf16bits(hi.x); af[5] = (short)bf16bits(hi.y);
            af[6] = (short)bf16bits(hi.z); af[7] = (short)bf16bits(hi.w);
        } else {
            #pragma unroll
            for (int j = 0; j < 8; ++j) {
                const int k = 288 + quad * 8 + j;
                af[j] = (k < E_) ? (short)bf16bits(arow[k]) : (short)0;
            }
        }
        #pragma unroll
        for (int j = 0; j < 8; ++j) {
            short8 bf = *(const short8*)(wp + (size_t)(j * 10 + ks) * 512);
            acc[j] = __builtin_amdgcn_mfma_f32_16x16x32_bf16(af, bf, acc[j], 0, 0, 0);
        }
    }
    #pragma unroll
    for (int j = 0; j < 8; ++j) {
        const float bias = bias2[blockIdx.y * 128 + j * 16 + l15];
        #pragma unroll
        for (int r = 0; r < 4; ++r)
            ct[wave][quad * 4 + r][j * 16 + l15] = bf16bits(acc[j][r] + bias);
    }
    #pragma unroll
    for (int i = 0; i < 4; ++i) {
        const int row = i * 4 + (lane >> 4);
        uint4 v = *(const uint4*)&ct[wave][row][l15 * 8];
        *(uint4*)(xprojb + (size_t)(m0 + row) * N2 + blockIdx.y * 128 + l15 * 8) = v;
    }
}

// ---------------------------------------------------------------------------
// K2: BiLSTM, DUAL-DIRECTION interleaved blocks. 32 blocks x 256 threads.
// grp = bx&3 (16 batches), slice = bx>>2 owns cells [slice*32,+32) of BOTH
// directions. Fwd W slice: 16 B-frags in 64 VGPRs (R4/R5-proven size; 256
// spills — R6). Bwd W slice: 64KB LDS in frag order (ds_read_b128).
// Per step t: [pollF|stage|B1][mfmaF|B2][cellF|publishF] then the same for
// bwd. Each chain's LLC handoff (publish -> poll) is hidden behind the
// OTHER chain's compute phase. Tag-in-data 8B atomics; no fences.
// ---------------------------------------------------------------------------
__global__ __launch_bounds__(256, 1) void k_lstm_dual(
    const ushort_t* __restrict__ xprojb,   // (64,128,2048) bf16
    const float*    __restrict__ w_hh_f,   // (1024,256) f32
    const float*    __restrict__ w_hh_b,
    const int*      __restrict__ text_len,
    u64*            __restrict__ hbuf,     // [2][2][4][16][128] tagged words
    float*          __restrict__ S)        // (64,512)
{
    __shared__ ushort_t wB[4 * 2 * 8 * 64 * 8];   // bwd W frags, 64 KB
    __shared__ ushort_t hlf[16][264];             // fwd h stage, pad +8
    __shared__ ushort_t hlb[16][264];             // bwd h stage
    __shared__ float    gLDS[4][16][33];          // gates, shared both phases

    const int tid   = threadIdx.x;
    const int grp   = blockIdx.x & 3;
    const int slice = blockIdx.x >> 2;
    const int b0    = grp * 16;
    const int j0    = slice * 32;
    const int wave  = tid >> 6, lane = tid & 63;
    const int quad  = lane >> 4, l15 = lane & 15;

    // ---- preload fwd W B-frags into registers (64 VGPRs) ----
    short8 wfrag[2][8];
    #pragma unroll
    for (int nt = 0; nt < 2; ++nt) {
        const int n = wave * 256 + j0 + nt * 16 + l15;
        const float* rowp = w_hh_f + (size_t)n * 256;
        #pragma unroll
        for (int ks = 0; ks < 8; ++ks) {
            const float* p = rowp + ks * 32 + quad * 8;
            float4 lo = *(const float4*)p;
            float4 hi = *(const float4*)(p + 4);
            short8 f;
            f[0] = (short)bf16bits(lo.x); f[1] = (short)bf16bits(lo.y);
            f[2] = (short)bf16bits(lo.z); f[3] = (short)bf16bits(lo.w);
            f[4] = (short)bf16bits(hi.x); f[5] = (short)bf16bits(hi.y);
            f[6] = (short)bf16bits(hi.z); f[7] = (short)bf16bits(hi.w);
            wfrag[nt][ks] = f;
        }
    }
    // ---- preload bwd W B-frags into LDS ----
    #pragma unroll
    for (int nt = 0; nt < 2; ++nt) {
        const int n = wave * 256 + j0 + nt * 16 + l15;
        const float* rowp = w_hh_b + (size_t)n * 256;
        #pragma unroll
        for (int ks = 0; ks < 8; ++ks) {
            const float* p = rowp + ks * 32 + quad * 8;
            float4 lo = *(const float4*)p;
            float4 hi = *(const float4*)(p + 4);
            short8 f;
            f[0] = (short)bf16bits(lo.x); f[1] = (short)bf16bits(lo.y);
            f[2] = (short)bf16bits(lo.z); f[3] = (short)bf16bits(lo.w);
            f[4] = (short)bf16bits(hi.x); f[5] = (short)bf16bits(hi.y);
            f[6] = (short)bf16bits(hi.z); f[7] = (short)bf16bits(hi.w);
            *(short8*)&wB[(size_t)((((wave * 2 + nt) * 8) + ks) * 64 + lane) * 8] = f;
        }
    }

    // thread roles: batch mb, cell pair c0 (= word w16), poll octet w16
    const int mb  = tid >> 4;
    const int w16 = tid & 15;
    const int c0  = w16 * 2;
    const int lenm = text_len[b0 + mb];
    float cstF0 = 0.f, cstF1 = 0.f, sF0 = 0.f, sF1 = 0.f;
    float cstB0 = 0.f, cstB1 = 0.f, sB0 = 0.f, sB1 = 0.f;

    u64* const hb = hbuf + (size_t)grp * 2048;   // [parity][dir] via offsets
    // parity p, dir d slab offset: (p*2 + d) * 8192
    __syncthreads();   // wB ready

    for (int t = 0; t < T_; ++t) {
        const int ttf = t, ttb = T_ - 1 - t;
        // xproj prefetch, both dirs (independent of h)
        const ushort_t* xpf = xprojb + ((size_t)(b0 + mb) * T_ + ttf) * N2 + j0;
        const ushort_t* xpb = xprojb + ((size_t)(b0 + mb) * T_ + ttb) * N2 + G4 + j0;
        unsigned xvF[4], xvB[4];
        #pragma unroll
        for (int q = 0; q < 4; ++q) {
            xvF[q] = *(const unsigned*)(xpf + q * 256 + c0);
            xvB[q] = *(const unsigned*)(xpb + q * 256 + c0);
        }

        // ================= PHASE F =================
        {   // poll fwd h_t (8 words/thread), stage to hlf
            const u64* src = hb + (size_t)((t & 1) * 2 + 0) * 8192 +
                             mb * 128 + w16 * 8;
            u64 v[8];
            for (;;) {
                bool ok = true;
                #pragma unroll
                for (int i = 0; i < 8; ++i)
                    v[i] = __hip_atomic_load(src + i, __ATOMIC_RELAXED,
                                             __HIP_MEMORY_SCOPE_AGENT);
                #pragma unroll
                for (int i = 0; i < 8; ++i)
                    ok = ok && ((unsigned)(v[i] >> 32) == (unsigned)t);
                if (ok) break;
            }
            uint4 a, b;
            a.x = (unsigned)v[0]; a.y = (unsigned)v[1];
            a.z = (unsigned)v[2]; a.w = (unsigned)v[3];
            b.x = (unsigned)v[4]; b.y = (unsigned)v[5];
            b.z = (unsigned)v[6]; b.w = (unsigned)v[7];
            *(uint4*)&hlf[mb][w16 * 16]     = a;
            *(uint4*)&hlf[mb][w16 * 16 + 8] = b;
        }
        __syncthreads();   // B1f
        {   // MFMA fwd: W from registers
            f32x4 acc0 = {}, acc1 = {};
            #pragma unroll
            for (int ks = 0; ks < 8; ++ks) {
                short8 af = *(const short8*)&hlf[l15][ks * 32 + quad * 8];
                acc0 = __builtin_amdgcn_mfma_f32_16x16x32_bf16(af, wfrag[0][ks], acc0, 0, 0, 0);
                acc1 = __builtin_amdgcn_mfma_f32_16x16x32_bf16(af, wfrag[1][ks], acc1, 0, 0, 0);
            }
            #pragma unroll
            for (int r = 0; r < 4; ++r) {
                gLDS[wave][quad * 4 + r][l15]      = acc0[r];
                gLDS[wave][quad * 4 + r][16 + l15] = acc1[r];
            }
        }
        __syncthreads();   // B2f
        {   // cell update fwd + publish
            const float gi0 = gLDS[0][mb][c0], gi1 = gLDS[0][mb][c0 + 1];
            const float gf0 = gLDS[1][mb][c0], gf1 = gLDS[1][mb][c0 + 1];
            const float gg0 = gLDS[2][mb][c0], gg1 = gLDS[2][mb][c0 + 1];
            const float go0 = gLDS[3][mb][c0], go1 = gLDS[3][mb][c0 + 1];
            const float i0 = sigm(bf16lo(xvF[0]) + gi0);
            const float i1 = sigm(bf16hi(xvF[0]) + gi1);
            const float f0 = sigm(bf16lo(xvF[1]) + gf0);
            const float f1 = sigm(bf16hi(xvF[1]) + gf1);
            const float g0 = tanh_fast(bf16lo(xvF[2]) + gg0);
            const float g1 = tanh_fast(bf16hi(xvF[2]) + gg1);
            const float o0 = sigm(bf16lo(xvF[3]) + go0);
            const float o1 = sigm(bf16hi(xvF[3]) + go1);
            cstF0 = f0 * cstF0 + i0 * g0;
            cstF1 = f1 * cstF1 + i1 * g1;
            const float h0 = o0 * tanh_fast(cstF0);
            const float h1 = o1 * tanh_fast(cstF1);
            if (ttf < lenm) { sF0 += h0; sF1 += h1; }
            const unsigned hp = (unsigned)bf16bits(h0) | ((unsigned)bf16bits(h1) << 16);
            u64* dst = hb + (size_t)(((t + 1) & 1) * 2 + 0) * 8192 +
                       mb * 128 + slice * 16 + w16;
            __hip_atomic_store(dst, ((u64)(unsigned)(t + 1) << 32) | (u64)hp,
                               __ATOMIC_RELAXED, __HIP_MEMORY_SCOPE_AGENT);
        }

        // ================= PHASE B =================
        {   // poll bwd h_t, stage to hlb
            const u64* src = hb + (size_t)((t & 1) * 2 + 1) * 8192 +
                             mb * 128 + w16 * 8;
            u64 v[8];
            for (;;) {
                bool ok = true;
                #pragma unroll
                for (int i = 0; i < 8; ++i)
                    v[i] = __hip_atomic_load(src + i, __ATOMIC_RELAXED,
                                             __HIP_MEMORY_SCOPE_AGENT);
                #pragma unroll
                for (int i = 0; i < 8; ++i)
                    ok = ok && ((unsigned)(v[i] >> 32) == (unsigned)t);
                if (ok) break;
            }
            uint4 a, b;
            a.x = (unsigned)v[0]; a.y = (unsigned)v[1];
            a.z = (unsigned)v[2]; a.w = (unsigned)v[3];
            b.x = (unsigned)v[4]; b.y = (unsigned)v[5];
            b.z = (unsigned)v[6]; b.w = (unsigned)v[7];
            *(uint4*)&hlb[mb][w16 * 16]     = a;
            *(uint4*)&hlb[mb][w16 * 16 + 8] = b;
        }
        __syncthreads();   // B1b (also: cellF gLDS reads done before this)
        {   // MFMA bwd: W from LDS
            f32x4 acc0 = {}, acc1 = {};
            #pragma unroll
            for (int ks = 0; ks < 8; ++ks) {
                short8 af  = *(const short8*)&hlb[l15][ks * 32 + quad * 8];
                short8 bf0 = *(const short8*)&wB[(size_t)((((wave * 2 + 0) * 8) + ks) * 64 + lane) * 8];
                short8 bf1 = *(const short8*)&wB[(size_t)((((wave * 2 + 1) * 8) + ks) * 64 + lane) * 8];
                acc0 = __builtin_amdgcn_mfma_f32_16x16x32_bf16(af, bf0, acc0, 0, 0, 0);
                acc1 = __builtin_amdgcn_mfma_f32_16x16x32_bf16(af, bf1, acc1, 0, 0, 0);
            }
            #pragma unroll
            for (int r = 0; r < 4; ++r) {
                gLDS[wave][quad * 4 + r][l15]      = acc0[r];
                gLDS[wave][quad * 4 + r][16 + l15] = acc1[r];
            }
        }
        __syncthreads();   // B2b
        {   // cell update bwd + publish
            const float gi0 = gLDS[0][mb][c0], gi1 = gLDS[0][mb][c0 + 1];
            const float gf0 = gLDS[1][mb][c0], gf1 = gLDS[1][mb][c0 + 1];
            const float gg0 = gLDS[2][mb][c0], gg1 = gLDS[2][mb][c0 + 1];
            const float go0 = gLDS[3][mb][c0], go1 = gLDS[3][mb][c0 + 1];
            const float i0 = sigm(bf16lo(xvB[0]) + gi0);
            const float i1 = sigm(bf16hi(xvB[0]) + gi1);
            const float f0 = sigm(bf16lo(xvB[1]) + gf0);
            const float f1 = sigm(bf16hi(xvB[1]) + gf1);
            const float g0 = tanh_fast(bf16lo(xvB[2]) + gg0);
            const float g1 = tanh_fast(bf16hi(xvB[2]) + gg1);
            const float o0 = sigm(bf16lo(xvB[3]) + go0);
            const float o1 = sigm(bf16hi(xvB[3]) + go1);
            cstB0 = f0 * cstB0 + i0 * g0;
            cstB1 = f1 * cstB1 + i1 * g1;
            const float h0 = o0 * tanh_fast(cstB0);
            const float h1 = o1 * tanh_fast(cstB1);
            if (ttb < lenm) { sB0 += h0; sB1 += h1; }
            const unsigned hp = (unsigned)bf16bits(h0) | ((unsigned)bf16bits(h1) << 16);
            u64* dst = hb + (size_t)(((t + 1) & 1) * 2 + 1) * 8192 +
                       mb * 128 + slice * 16 + w16;
            __hip_atomic_store(dst, ((u64)(unsigned)(t + 1) << 32) | (u64)hp,
                               __ATOMIC_RELAXED, __HIP_MEMORY_SCOPE_AGENT);
        }
        __syncthreads();   // B3: gLDS/hl reuse fence for next iteration
    }

    float* sp = S + (size_t)(b0 + mb) * GG + j0 + c0;
    float2 svf; svf.x = sF0; svf.y = sF1;
    float2 svb; svb.x = sB0; svb.y = sB1;
    *(float2*)sp = svf;
    *(float2*)(sp + H_) = svb;
}

// ---------------------------------------------------------------------------
// K3: head (unchanged).
// ---------------------------------------------------------------------------
__global__ __launch_bounds__(256) void k_head(
    const float* __restrict__ S,
    const int*   __restrict__ text_len,
    const float* __restrict__ gat_w, const float* __restrict__ gat_b,
    const float* __restrict__ fc1_w, const float* __restrict__ fc1_b,
    const float* __restrict__ fc2_w, const float* __restrict__ fc2_b,
    const float* __restrict__ fcf_w, const float* __restrict__ fcf_b,
    float* __restrict__ out)
{
    __shared__ float sb[GG];
    __shared__ float x1[GG];
    __shared__ float x2[FH_];
    __shared__ float x3[FH_];
    const int b = blockIdx.x, tid = threadIdx.x;
    sb[tid]       = S[(size_t)b * GG + tid];
    sb[tid + 256] = S[(size_t)b * GG + tid + 256];
    __syncthreads();
    const float lenf = (float)text_len[b];
    #pragma unroll
    for (int r = 0; r < 2; ++r) {
        const int n = tid + r * 256;
        float acc = gat_b[n] * lenf;
        const float* w = gat_w + (size_t)n * GG;
        for (int k = 0; k < GG; ++k) acc += sb[k] * w[k];
        x1[n] = fmaxf(acc, 0.f);
    }
    __syncthreads();
    {
        float acc = fc1_b[tid];
        const float* w = fc1_w + (size_t)tid * GG;
        for (int k = 0; k < GG; ++k) acc += x1[k] * w[k];
        x2[tid] = fmaxf(acc, 0.f);
    }
    __syncthreads();
    {
        float acc = fc2_b[tid];
        const float* w = fc2_w + (size_t)tid * FH_;
        for (int k = 0; k < FH_; ++k) acc += x2[k] * w[k];
        x3[tid] = fmaxf(acc, 0.f);
    }
    __syncthreads();
    if (tid < NC_) {
        float acc = fcf_b[tid];
        const float* w = fcf_w + (size_t)tid * FH_;
        for (int k = 0; k < FH_; ++k) acc += x3[k] * w[k];
        out[b * NC_ + tid] = acc;
    }
}

// ---------------------------------------------------------------------------
extern "C" void kernel_launch(void* const* d_in, const int* in_sizes, int n_in,
                              void* d_out, int out_size, void* d_ws, size_t ws_size,
                              hipStream_t stream) {
    const int*   sentence = (const int*)  d_in[0];
    const int*   text_len = (const int*)  d_in[4];
    const float* glove    = (const float*)d_in[10];
    const float* w_ih_f   = (const float*)d_in[11];
    const float* w_hh_f   = (const float*)d_in[12];
    const float* b_ih_f   = (const float*)d_in[13];
    const float* b_hh_f   = (const float*)d_in[14];
    const float* w_ih_b   = (const float*)d_in[15];
    const float* w_hh_b   = (const float*)d_in[16];
    const float* b_ih_b   = (const float*)d_in[17];
    const float* b_hh_b   = (const float*)d_in[18];
    const float* gat_w    = (const float*)d_in[19];
    const float* gat_b    = (const float*)d_in[20];
    const float* fc1_w    = (const float*)d_in[21];
    const float* fc1_b    = (const float*)d_in[22];
    const float* fc2_w    = (const float*)d_in[23];
    const float* fc2_b    = (const float*)d_in[24];
    const float* fcf_w    = (const float*)d_in[25];
    const float* fcf_b    = (const float*)d_in[26];
    float* out = (float*)d_out;

    char* ws = (char*)d_ws;
    u64*      hbuf    = (u64*)ws;
    float*    bias2   = (float*)(ws + OFF_BIAS);
    ushort_t* wihshuf = (ushort_t*)(ws + OFF_WIH);
    ushort_t* xprojb  = (ushort_t*)(ws + OFF_XPROJ);
    float*    S       = (float*)(ws + OFF_S);

    k_prep<<<320, 256, 0, stream>>>(w_ih_f, w_ih_b,
                                    b_ih_f, b_hh_f, b_ih_b, b_hh_b,
                                    hbuf, bias2, wihshuf);
    dim3 gx(128, 16);
    k_xproj_mfma<<<gx, 256, 0, stream>>>(sentence, glove, wihshuf, bias2, xprojb);
    k_lstm_dual<<<32, 256, 0, stream>>>(xprojb, w_hh_f, w_hh_b, text_len,
                                        hbuf, S);
    k_head<<<64, 256, 0, stream>>>(S, text_len, gat_w, gat_b,
                                   fc1_w, fc1_b, fc2_w, fc2_b,
                                   fcf_w, fcf_b, out);
}